// Round 15
// baseline (55.288 us; speedup 1.0000x reference)
//
#include <hip/hip_runtime.h>

#define NN 10000
#define DF 128
#define NE 640000
#define GBN 16                    // nodes per bucket
#define NBUCK 625                 // NN/16
#define TILE 4096
#define NTILES ((NE + TILE - 1) / TILE)   // 157
#define GCAP 2048                 // bucket entry capacity (E=1024, sd~32)

#define PACK_BLKS 157             // ceil(NN*16 / 1024) : 4 u32 per thread
#define PREP_BLKS 16              // 128 o-rows / 8

typedef __attribute__((ext_vector_type(8))) short bf16x8;
typedef __attribute__((ext_vector_type(4))) float f32x4;
typedef unsigned long long ull;

__device__ __forceinline__ unsigned int f2bf(float f) {
    unsigned int u = __float_as_uint(f);
    u = (u + 0x7FFFu + ((u >> 16) & 1u)) >> 16;   // RNE
    return u;
}
__device__ __forceinline__ unsigned int pack2bf(float a, float b) {
    return f2bf(a) | (f2bf(b) << 16);
}
__device__ __forceinline__ float bf_lo(unsigned int v) { return __uint_as_float(v << 16); }
__device__ __forceinline__ float bf_hi(unsigned int v) { return __uint_as_float(v & 0xFFFF0000u); }

// ---------------------------------------------------------------------------
// P: fused prologue. blockIdx roles:
//   [0, 157)      : pack feat -> A_bf bf16-pair u32, 4 u32/thread
//   [157, 314)    : per-(tile,bucket) histogram -> tbl[t*NBUCK+b] (1 int4/thr)
//   [314, 330)    : prep: wprod = Wfc2 @ W_src, pack Bw bf16, bsrc2
// ---------------------------------------------------------------------------
__global__ __launch_bounds__(1024) void prologue(const float* __restrict__ feat,
                                                 unsigned int* __restrict__ A_bf,
                                                 const int* __restrict__ dstv,
                                                 int* __restrict__ tbl,
                                                 const float* __restrict__ Wfc,
                                                 const float* __restrict__ Wsrc,
                                                 const float* __restrict__ bsrc,
                                                 unsigned int* __restrict__ Bw,
                                                 float* __restrict__ bsrc2)
{
    const int bx = blockIdx.x, tid = threadIdx.x;

    if (bx < PACK_BLKS) {
        const int id = bx * 1024 + tid;          // u32-quad index, < 160000
        if (id < NN * 16) {
            const int row = id >> 4, j4 = id & 15;    // 8 feats starting 8*j4
            const float4 fa = *(const float4*)(feat + (size_t)row * DF + 8 * j4);
            const float4 fb = *(const float4*)(feat + (size_t)row * DF + 8 * j4 + 4);
            uint4 v;
            v.x = pack2bf(fa.x, fa.y); v.y = pack2bf(fa.z, fa.w);
            v.z = pack2bf(fb.x, fb.y); v.w = pack2bf(fb.z, fb.w);
            *(uint4*)(A_bf + (size_t)row * 64 + 4 * j4) = v;
        }
        return;
    }
    if (bx < PACK_BLKS + NTILES) {
        __shared__ int h[NBUCK];
        const int t = bx - PACK_BLKS;
        if (tid < NBUCK) h[tid] = 0;
        __syncthreads();
        const int e0 = t * TILE;
        const int n = min(TILE, NE - e0);
        const int eb = 4 * tid;
        if (eb < n) {
            const int4 dd = *(const int4*)(dstv + e0 + eb);
            atomicAdd(&h[dd.x >> 4], 1);
            atomicAdd(&h[dd.y >> 4], 1);
            atomicAdd(&h[dd.z >> 4], 1);
            atomicAdd(&h[dd.w >> 4], 1);
        }
        __syncthreads();
        if (tid < NBUCK) tbl[t * NBUCK + tid] = h[tid];
        return;
    }
    {   // prep: 16 blocks x 8 output rows; group g = 128 threads
        __shared__ float wp[8][128];
        __shared__ float red[16];
        const int g = tid >> 7;                 // 0..7
        const int k = tid & 127;
        const int o = (bx - PACK_BLKS - NTILES) * 8 + g;
        const float* w2 = Wfc + (size_t)o * 256 + 128;   // uniform -> s_load
        float acc = 0.f;
#pragma unroll 8
        for (int j = 0; j < 128; ++j)
            acc = fmaf(w2[j], Wsrc[j * 128 + k], acc);
        wp[g][k] = acc;

        float p = w2[k] * bsrc[k];
#pragma unroll
        for (int d = 32; d > 0; d >>= 1) p += __shfl_down(p, d);
        if ((tid & 63) == 0) red[tid >> 6] = p;
        __syncthreads();
        if (k < 64) {
            const float2 wf = *(const float2*)(Wfc + (size_t)o * 256 + 2 * k);
            Bw[(size_t)o * 128 + k] = pack2bf(wf.x, wf.y);
            Bw[(size_t)o * 128 + 64 + k] = pack2bf(wp[g][2 * k], wp[g][2 * k + 1]);
        }
        if (k == 0) bsrc2[o] = red[2 * g] + red[2 * g + 1];
    }
}

// ---------------------------------------------------------------------------
// B: binning with INLINE offset derivation. Thread b streams tbl[t][b]
// (coalesced); packed 64-bit shuffle scan gives off[b] (hi) / lbase[b] (lo).
// 157 blocks x 4096-edge tiles (was 79x8192 -> 2x parallelism). int4 edge
// ingestion; LDS bucket-sort + coalesced flush into disjoint precomputed
// runs. Zero global atomics; deterministic; replay-safe.
// ---------------------------------------------------------------------------
__global__ __launch_bounds__(1024) void bin2(const int* __restrict__ srcv,
                                             const int* __restrict__ dstv,
                                             const int* __restrict__ tbl,
                                             unsigned int* __restrict__ ents,
                                             int* __restrict__ off_g)
{
    __shared__ unsigned int ent[TILE];   // 16 KB
    __shared__ ull wpart[16];
    __shared__ int lbase[NBUCK];
    __shared__ int lcur[NBUCK];
    __shared__ int gbase[NBUCK];

    const int tid = threadIdx.x;
    const int lane = tid & 63, wid = tid >> 6;
    const int bx = blockIdx.x;
    const int e0 = bx * TILE;
    const int n = min(TILE, NE - e0);   // multiple of 4

    int myd[4], mys[4];
    {
        const int eb = 4 * tid;
        if (eb < n) {
            const int4 dd = *(const int4*)(dstv + e0 + eb);
            const int4 ss = *(const int4*)(srcv + e0 + eb);
            myd[0] = dd.x; myd[1] = dd.y; myd[2] = dd.z; myd[3] = dd.w;
            mys[0] = ss.x; mys[1] = ss.y; mys[2] = ss.z; mys[3] = ss.w;
        } else {
#pragma unroll
            for (int q = 0; q < 4; ++q) { myd[q] = -1; mys[q] = 0; }
        }
    }

    // per-bucket: pre (edges in earlier tiles), myh (this tile), tot
    int pre = 0, tot = 0, myh = 0;
    if (tid < NBUCK) {
#pragma unroll 8
        for (int t = 0; t < NTILES; ++t) {
            const int c = tbl[t * NBUCK + tid];
            pre += (t < bx) ? c : 0;
            myh += (t == bx) ? c : 0;
            tot += c;
        }
    }
    // packed dual exclusive scan over 625 buckets: hi=tot, lo=myh
    const ull v = (tid < NBUCK) ? (((ull)(unsigned)tot << 32) | (unsigned)myh) : 0ull;
    ull inc = v;
#pragma unroll
    for (int d = 1; d < 64; d <<= 1) {
        const ull x = (ull)__shfl_up((unsigned long long)inc, d);
        if (lane >= d) inc += x;
    }
    if (lane == 63) wpart[wid] = inc;
    __syncthreads();
    ull wsum = 0;
    for (int w = 0; w < wid; ++w) wsum += wpart[w];
    const ull ex = wsum + inc - v;
    if (tid < NBUCK) {
        const int offb = (int)(ex >> 32);
        lbase[tid] = (int)(ex & 0xFFFFFFFFull);
        gbase[tid] = offb + pre;
        lcur[tid] = 0;
        if (bx == 0) {
            off_g[tid] = offb;
            if (tid == NBUCK - 1) off_g[NBUCK] = (int)((ex + v) >> 32);
        }
    }
    __syncthreads();

    // local scatter into bucket-sorted LDS order (int LDS atomics only)
#pragma unroll
    for (int j = 0; j < 4; ++j) {
        if (myd[j] >= 0) {
            const int b = myd[j] >> 4;
            const int p = atomicAdd(&lcur[b], 1);
            ent[lbase[b] + p] = ((unsigned)myd[j] << 14) | (unsigned)mys[j];
        }
    }
    __syncthreads();

    // coalesced flush into disjoint precomputed global runs
    for (int i = tid; i < n; i += 1024) {
        const unsigned u = ent[i];
        const int b = (int)(u >> 18);        // dst>>4
        ents[gbase[b] + (i - lbase[b])] = u;
    }
}

// ---------------------------------------------------------------------------
// GA: fused gather + MFMA apply. Block b owns nodes [16b, 16b+16) == the
// 16-row output stripe. 512 threads = 8 waves, 2 nodes/wave.
// Gather loads are uint4 (16B/lane): lane = slot(4) x featlane(16); one
// VMEM instruction covers 4 edge rows (1KB). Per-slot partials combined
// with 2 shfl_xor steps. Phase 2: 16x128 MFMA stripe, 1 col-tile/wave.
// D mapping (m89): col=lane&15, row=(lane>>4)*4+reg.
// ---------------------------------------------------------------------------
__global__ __launch_bounds__(512) void gather_apply(const unsigned int* __restrict__ A_bf,
                                                    const unsigned int* __restrict__ Bw,
                                                    const unsigned int* __restrict__ ents,
                                                    const int* __restrict__ off,
                                                    const float* __restrict__ bfc,
                                                    const float* __restrict__ bsrc2,
                                                    float* __restrict__ out)
{
    __shared__ unsigned int raw[GCAP];       // 8 KB
    __shared__ unsigned short sorted[GCAP];  // 4 KB
    __shared__ int h[GBN], base[GBN], cur[GBN];
    __shared__ unsigned int ntile[GBN][68];  // neigh bf16 pairs, 272B rows (16B-mult)

    const int tid = threadIdx.x;
    const int b = blockIdx.x;
    const int rbase = b * GBN;
    const int r0 = off[b], r1 = off[b + 1];
    const int cnt = min(r1 - r0, GCAP);

    if (tid < GBN) { h[tid] = 0; cur[tid] = 0; }
    __syncthreads();
    for (int i = tid; i < cnt; i += 512) {
        const unsigned u = ents[r0 + i];
        raw[i] = u;
        atomicAdd(&h[(u >> 14) & (GBN - 1)], 1);
    }
    __syncthreads();
    if (tid == 0) {
        int s = 0;
#pragma unroll
        for (int j = 0; j < GBN; ++j) { base[j] = s; s += h[j]; }
    }
    __syncthreads();
    for (int i = tid; i < cnt; i += 512) {
        const unsigned u = raw[i];
        const int dl = (int)((u >> 14) & (GBN - 1));
        const int p = base[dl] + atomicAdd(&cur[dl], 1);
        sorted[p] = (unsigned short)(u & 0x3FFFu);
    }
    __syncthreads();

    const int wave = tid >> 6, lane = tid & 63;
    const int slot = lane >> 4, fl = lane & 15;
#pragma unroll
    for (int j = 0; j < 2; ++j) {
        const int dl = wave * 2 + j;
        const int s0 = base[dl], n = h[dl];
        float s[8] = {0.f, 0.f, 0.f, 0.f, 0.f, 0.f, 0.f, 0.f};
        int i = 0;
        for (; i + 8 <= n; i += 8) {
            const int ra = sorted[s0 + i + slot];
            const int rb = sorted[s0 + i + 4 + slot];
            const uint4 va = *(const uint4*)(A_bf + (size_t)ra * 64 + fl * 4);
            const uint4 vb = *(const uint4*)(A_bf + (size_t)rb * 64 + fl * 4);
            s[0] += bf_lo(va.x) + bf_lo(vb.x); s[1] += bf_hi(va.x) + bf_hi(vb.x);
            s[2] += bf_lo(va.y) + bf_lo(vb.y); s[3] += bf_hi(va.y) + bf_hi(vb.y);
            s[4] += bf_lo(va.z) + bf_lo(vb.z); s[5] += bf_hi(va.z) + bf_hi(vb.z);
            s[6] += bf_lo(va.w) + bf_lo(vb.w); s[7] += bf_hi(va.w) + bf_hi(vb.w);
        }
        for (; i < n; i += 4) {
            if (i + slot < n) {
                const int ra = sorted[s0 + i + slot];
                const uint4 va = *(const uint4*)(A_bf + (size_t)ra * 64 + fl * 4);
                s[0] += bf_lo(va.x); s[1] += bf_hi(va.x);
                s[2] += bf_lo(va.y); s[3] += bf_hi(va.y);
                s[4] += bf_lo(va.z); s[5] += bf_hi(va.z);
                s[6] += bf_lo(va.w); s[7] += bf_hi(va.w);
            }
        }
        // combine the 4 slots (lanes fl, fl+16, fl+32, fl+48)
#pragma unroll
        for (int q = 0; q < 8; ++q) {
            s[q] += __shfl_xor(s[q], 16);
            s[q] += __shfl_xor(s[q], 32);
        }
        if (slot == 0) {
            const float inv = (n > 0) ? 1.f / (float)n : 0.f;
            uint4 o;
            o.x = pack2bf(s[0] * inv, s[1] * inv);
            o.y = pack2bf(s[2] * inv, s[3] * inv);
            o.z = pack2bf(s[4] * inv, s[5] * inv);
            o.w = pack2bf(s[6] * inv, s[7] * inv);
            *(uint4*)(&ntile[dl][fl * 4]) = o;
        }
    }
    __syncthreads();

    // ---- Phase 2: MFMA stripe (16 rows x 128 cols, K=256), 1 tile/wave ----
    const int r = lane & 15, kg = lane >> 4;

    const unsigned int* ap = A_bf + (size_t)(rbase + r) * 64 + kg * 4;
    bf16x8 a[8];
#pragma unroll
    for (int s = 0; s < 4; ++s) a[s] = *(const bf16x8*)(ap + s * 16);
#pragma unroll
    for (int s = 0; s < 4; ++s) a[4 + s] = *(const bf16x8*)(&ntile[r][s * 16 + kg * 4]);

    bool hd[4];
#pragma unroll
    for (int q = 0; q < 4; ++q) hd[q] = h[kg * 4 + q] > 0;

    const int cbase = wave * 16;
    const unsigned int* bp = Bw + (size_t)(cbase + r) * 128 + kg * 4;
    bf16x8 bb[8];
#pragma unroll
    for (int s = 0; s < 8; ++s) bb[s] = *(const bf16x8*)(bp + s * 16);
    f32x4 acc = {0.f, 0.f, 0.f, 0.f};
#pragma unroll
    for (int s = 0; s < 8; ++s)
        acc = __builtin_amdgcn_mfma_f32_16x16x32_bf16(a[s], bb[s], acc, 0, 0, 0);

    const int col = cbase + r;
    const float bc = bfc[col], bs = bsrc2[col];
#pragma unroll
    for (int q = 0; q < 4; ++q) {
        const int row = rbase + kg * 4 + q;
        out[(size_t)row * DF + col] = acc[q] + bc + (hd[q] ? bs : 0.f);
    }
}

extern "C" void kernel_launch(void* const* d_in, const int* in_sizes, int n_in,
                              void* d_out, int out_size, void* d_ws, size_t ws_size,
                              hipStream_t stream) {
    const float* feat  = (const float*)d_in[0];
    const float* W_src = (const float*)d_in[1];
    const float* b_src = (const float*)d_in[2];
    const float* W_fc  = (const float*)d_in[3];
    const float* b_fc  = (const float*)d_in[4];
    const int*   src   = (const int*)d_in[5];
    const int*   dst   = (const int*)d_in[6];
    float* out = (float*)d_out;

    // ws: A_bf [NN*64 u32] | Bw [128*128 u32] | bsrc2 [128 f32] |
    //     off [NBUCK+1] | tbl [NTILES*NBUCK] | ents [NE u32]
    unsigned int* A_bf = (unsigned int*)d_ws;
    unsigned int* Bw = A_bf + (size_t)NN * 64;
    float* bsrc2 = (float*)(Bw + 128 * 128);
    int*   off   = (int*)(bsrc2 + 128);
    int*   tbl   = off + (NBUCK + 1);
    unsigned int* ents = (unsigned int*)(tbl + (size_t)NTILES * NBUCK);

    prologue    <<<PACK_BLKS + NTILES + PREP_BLKS, 1024, 0, stream>>>(
                    feat, A_bf, dst, tbl, W_fc, W_src, b_src, Bw, bsrc2);
    bin2        <<<NTILES, 1024, 0, stream>>>(src, dst, tbl, ents, off);
    gather_apply<<<NBUCK, 512, 0, stream>>>(A_bf, Bw, ents, off, b_fc, bsrc2, out);
}

// Round 16
// 50.222 us; speedup vs baseline: 1.1009x; 1.1009x over previous
//
#include <hip/hip_runtime.h>

#define NN 10000
#define DF 128
#define NE 640000
#define GBN 16                    // nodes per bucket
#define NBUCK 625                 // NN/16
#define TILE 8192
#define NTILES ((NE + TILE - 1) / TILE)   // 79
#define GCAP 2048                 // bucket entry capacity (E=1024, sd~32)

#define PACK_BLKS 157             // ceil(NN*16 / 1024) : 4 u32 per thread
#define PREP_BLKS 16              // 128 o-rows / 8

typedef __attribute__((ext_vector_type(8))) short bf16x8;
typedef __attribute__((ext_vector_type(4))) float f32x4;
typedef unsigned long long ull;

__device__ __forceinline__ unsigned int f2bf(float f) {
    unsigned int u = __float_as_uint(f);
    u = (u + 0x7FFFu + ((u >> 16) & 1u)) >> 16;   // RNE
    return u;
}
__device__ __forceinline__ unsigned int pack2bf(float a, float b) {
    return f2bf(a) | (f2bf(b) << 16);
}
__device__ __forceinline__ float bf_lo(unsigned int v) { return __uint_as_float(v << 16); }
__device__ __forceinline__ float bf_hi(unsigned int v) { return __uint_as_float(v & 0xFFFF0000u); }

// ---------------------------------------------------------------------------
// P: fused prologue. blockIdx roles:
//   [0, 157)    : pack feat -> A_bf bf16-pair u32, 4 u32/thread (vectorized)
//   [157, 236)  : per-(tile,bucket) histogram -> tbl[t*NBUCK+b]
//   [236, 252)  : prep: wprod = Wfc2 @ W_src, pack Bw bf16, bsrc2
// ---------------------------------------------------------------------------
__global__ __launch_bounds__(1024) void prologue(const float* __restrict__ feat,
                                                 unsigned int* __restrict__ A_bf,
                                                 const int* __restrict__ dstv,
                                                 int* __restrict__ tbl,
                                                 const float* __restrict__ Wfc,
                                                 const float* __restrict__ Wsrc,
                                                 const float* __restrict__ bsrc,
                                                 unsigned int* __restrict__ Bw,
                                                 float* __restrict__ bsrc2)
{
    const int bx = blockIdx.x, tid = threadIdx.x;

    if (bx < PACK_BLKS) {
        const int id = bx * 1024 + tid;          // u32-quad index, < 160000
        if (id < NN * 16) {
            const int row = id >> 4, j4 = id & 15;    // 8 feats starting 8*j4
            const float4 fa = *(const float4*)(feat + (size_t)row * DF + 8 * j4);
            const float4 fb = *(const float4*)(feat + (size_t)row * DF + 8 * j4 + 4);
            uint4 v;
            v.x = pack2bf(fa.x, fa.y); v.y = pack2bf(fa.z, fa.w);
            v.z = pack2bf(fb.x, fb.y); v.w = pack2bf(fb.z, fb.w);
            *(uint4*)(A_bf + (size_t)row * 64 + 4 * j4) = v;
        }
        return;
    }
    if (bx < PACK_BLKS + NTILES) {
        __shared__ int h[NBUCK];
        const int t = bx - PACK_BLKS;
        if (tid < NBUCK) h[tid] = 0;
        __syncthreads();
        const int e0 = t * TILE;
        const int n = min(TILE, NE - e0);
#pragma unroll
        for (int j = 0; j < 2; ++j) {
            const int eb = 4 * (tid + j * 1024);
            if (eb < n) {
                const int4 dd = *(const int4*)(dstv + e0 + eb);
                atomicAdd(&h[dd.x >> 4], 1);
                atomicAdd(&h[dd.y >> 4], 1);
                atomicAdd(&h[dd.z >> 4], 1);
                atomicAdd(&h[dd.w >> 4], 1);
            }
        }
        __syncthreads();
        if (tid < NBUCK) tbl[t * NBUCK + tid] = h[tid];
        return;
    }
    {   // prep: 16 blocks x 8 output rows; group g = 128 threads
        __shared__ float wp[8][128];
        __shared__ float red[16];
        const int g = tid >> 7;                 // 0..7
        const int k = tid & 127;
        const int o = (bx - PACK_BLKS - NTILES) * 8 + g;
        const float* w2 = Wfc + (size_t)o * 256 + 128;   // uniform -> s_load
        float acc = 0.f;
#pragma unroll 8
        for (int j = 0; j < 128; ++j)
            acc = fmaf(w2[j], Wsrc[j * 128 + k], acc);
        wp[g][k] = acc;

        float p = w2[k] * bsrc[k];
#pragma unroll
        for (int d = 32; d > 0; d >>= 1) p += __shfl_down(p, d);
        if ((tid & 63) == 0) red[tid >> 6] = p;
        __syncthreads();
        if (k < 64) {
            const float2 wf = *(const float2*)(Wfc + (size_t)o * 256 + 2 * k);
            Bw[(size_t)o * 128 + k] = pack2bf(wf.x, wf.y);
            Bw[(size_t)o * 128 + 64 + k] = pack2bf(wp[g][2 * k], wp[g][2 * k + 1]);
        }
        if (k == 0) bsrc2[o] = red[2 * g] + red[2 * g + 1];
    }
}

// ---------------------------------------------------------------------------
// B: binning with INLINE offset derivation. Thread b streams tbl[t][b]
// (coalesced); packed 64-bit shuffle scan gives off[b] (hi) / lbase[b] (lo).
// Vectorized int4 edge ingestion. LDS bucket-sort + coalesced flush into
// disjoint precomputed runs. Zero global atomics; replay-safe.
// NOTE: offset derivation streams the whole tbl per block -> O(NTILES^2)
// traffic; at TILE=8192/NTILES=79 this is 15.6 MB (fine). TILE=4096
// quadrupled it and regressed (r15). Keep TILE=8192.
// ---------------------------------------------------------------------------
__global__ __launch_bounds__(1024) void bin2(const int* __restrict__ srcv,
                                             const int* __restrict__ dstv,
                                             const int* __restrict__ tbl,
                                             unsigned int* __restrict__ ents,
                                             int* __restrict__ off_g)
{
    __shared__ unsigned int ent[TILE];   // 32 KB
    __shared__ ull wpart[16];
    __shared__ int lbase[NBUCK];
    __shared__ int lcur[NBUCK];
    __shared__ int gbase[NBUCK];

    const int tid = threadIdx.x;
    const int lane = tid & 63, wid = tid >> 6;
    const int bx = blockIdx.x;
    const int e0 = bx * TILE;
    const int n = min(TILE, NE - e0);   // always a multiple of 4

    int myd[8], mys[8];
#pragma unroll
    for (int j = 0; j < 2; ++j) {
        const int eb = 4 * (tid + j * 1024);
        if (eb < n) {
            const int4 dd = *(const int4*)(dstv + e0 + eb);
            const int4 ss = *(const int4*)(srcv + e0 + eb);
            myd[4*j+0] = dd.x; myd[4*j+1] = dd.y; myd[4*j+2] = dd.z; myd[4*j+3] = dd.w;
            mys[4*j+0] = ss.x; mys[4*j+1] = ss.y; mys[4*j+2] = ss.z; mys[4*j+3] = ss.w;
        } else {
#pragma unroll
            for (int q = 0; q < 4; ++q) { myd[4*j+q] = -1; mys[4*j+q] = 0; }
        }
    }

    // per-bucket: pre (edges in earlier tiles), myh (this tile), tot
    int pre = 0, tot = 0, myh = 0;
    if (tid < NBUCK) {
#pragma unroll 8
        for (int t = 0; t < NTILES; ++t) {
            const int c = tbl[t * NBUCK + tid];
            pre += (t < bx) ? c : 0;
            myh += (t == bx) ? c : 0;
            tot += c;
        }
    }
    // packed dual exclusive scan over 625 buckets: hi=tot, lo=myh
    const ull v = (tid < NBUCK) ? (((ull)(unsigned)tot << 32) | (unsigned)myh) : 0ull;
    ull inc = v;
#pragma unroll
    for (int d = 1; d < 64; d <<= 1) {
        const ull x = (ull)__shfl_up((unsigned long long)inc, d);
        if (lane >= d) inc += x;
    }
    if (lane == 63) wpart[wid] = inc;
    __syncthreads();
    ull wsum = 0;
    for (int w = 0; w < wid; ++w) wsum += wpart[w];
    const ull ex = wsum + inc - v;
    if (tid < NBUCK) {
        const int offb = (int)(ex >> 32);
        lbase[tid] = (int)(ex & 0xFFFFFFFFull);
        gbase[tid] = offb + pre;
        lcur[tid] = 0;
        if (bx == 0) {
            off_g[tid] = offb;
            if (tid == NBUCK - 1) off_g[NBUCK] = (int)((ex + v) >> 32);
        }
    }
    __syncthreads();

    // local scatter into bucket-sorted LDS order (int LDS atomics only)
#pragma unroll
    for (int j = 0; j < 8; ++j) {
        if (myd[j] >= 0) {
            const int b = myd[j] >> 4;
            const int p = atomicAdd(&lcur[b], 1);
            ent[lbase[b] + p] = ((unsigned)myd[j] << 14) | (unsigned)mys[j];
        }
    }
    __syncthreads();

    // coalesced flush into disjoint precomputed global runs
    for (int i = tid; i < n; i += 1024) {
        const unsigned u = ent[i];
        const int b = (int)(u >> 18);        // dst>>4
        ents[gbase[b] + (i - lbase[b])] = u;
    }
}

// ---------------------------------------------------------------------------
// GA: fused gather + MFMA apply. Block b owns nodes [16b, 16b+16) == the
// 16-row output stripe. 512 threads = 8 waves, 2 nodes/wave.
// Gather loads are uint4 (16B/lane): lane = slot(4) x featlane(16); one
// VMEM instruction covers 4 edge rows (1KB). Per-slot partials combined
// with 2 shfl_xor steps. Phase 2: 16x128 MFMA stripe, 1 col-tile/wave.
// D mapping (m89): col=lane&15, row=(lane>>4)*4+reg.
// ---------------------------------------------------------------------------
__global__ __launch_bounds__(512) void gather_apply(const unsigned int* __restrict__ A_bf,
                                                    const unsigned int* __restrict__ Bw,
                                                    const unsigned int* __restrict__ ents,
                                                    const int* __restrict__ off,
                                                    const float* __restrict__ bfc,
                                                    const float* __restrict__ bsrc2,
                                                    float* __restrict__ out)
{
    __shared__ unsigned int raw[GCAP];       // 8 KB
    __shared__ unsigned short sorted[GCAP];  // 4 KB
    __shared__ int h[GBN], base[GBN], cur[GBN];
    __shared__ unsigned int ntile[GBN][68];  // neigh bf16 pairs, 272B rows (16B-mult)

    const int tid = threadIdx.x;
    const int b = blockIdx.x;
    const int rbase = b * GBN;
    const int r0 = off[b], r1 = off[b + 1];
    const int cnt = min(r1 - r0, GCAP);

    if (tid < GBN) { h[tid] = 0; cur[tid] = 0; }
    __syncthreads();
    for (int i = tid; i < cnt; i += 512) {
        const unsigned u = ents[r0 + i];
        raw[i] = u;
        atomicAdd(&h[(u >> 14) & (GBN - 1)], 1);
    }
    __syncthreads();
    if (tid == 0) {
        int s = 0;
#pragma unroll
        for (int j = 0; j < GBN; ++j) { base[j] = s; s += h[j]; }
    }
    __syncthreads();
    for (int i = tid; i < cnt; i += 512) {
        const unsigned u = raw[i];
        const int dl = (int)((u >> 14) & (GBN - 1));
        const int p = base[dl] + atomicAdd(&cur[dl], 1);
        sorted[p] = (unsigned short)(u & 0x3FFFu);
    }
    __syncthreads();

    const int wave = tid >> 6, lane = tid & 63;
    const int slot = lane >> 4, fl = lane & 15;
#pragma unroll
    for (int j = 0; j < 2; ++j) {
        const int dl = wave * 2 + j;
        const int s0 = base[dl], n = h[dl];
        float s[8] = {0.f, 0.f, 0.f, 0.f, 0.f, 0.f, 0.f, 0.f};
        int i = 0;
        for (; i + 8 <= n; i += 8) {
            const int ra = sorted[s0 + i + slot];
            const int rb = sorted[s0 + i + 4 + slot];
            const uint4 va = *(const uint4*)(A_bf + (size_t)ra * 64 + fl * 4);
            const uint4 vb = *(const uint4*)(A_bf + (size_t)rb * 64 + fl * 4);
            s[0] += bf_lo(va.x) + bf_lo(vb.x); s[1] += bf_hi(va.x) + bf_hi(vb.x);
            s[2] += bf_lo(va.y) + bf_lo(vb.y); s[3] += bf_hi(va.y) + bf_hi(vb.y);
            s[4] += bf_lo(va.z) + bf_lo(vb.z); s[5] += bf_hi(va.z) + bf_hi(vb.z);
            s[6] += bf_lo(va.w) + bf_lo(vb.w); s[7] += bf_hi(va.w) + bf_hi(vb.w);
        }
        for (; i < n; i += 4) {
            if (i + slot < n) {
                const int ra = sorted[s0 + i + slot];
                const uint4 va = *(const uint4*)(A_bf + (size_t)ra * 64 + fl * 4);
                s[0] += bf_lo(va.x); s[1] += bf_hi(va.x);
                s[2] += bf_lo(va.y); s[3] += bf_hi(va.y);
                s[4] += bf_lo(va.z); s[5] += bf_hi(va.z);
                s[6] += bf_lo(va.w); s[7] += bf_hi(va.w);
            }
        }
        // combine the 4 slots (lanes fl, fl+16, fl+32, fl+48)
#pragma unroll
        for (int q = 0; q < 8; ++q) {
            s[q] += __shfl_xor(s[q], 16);
            s[q] += __shfl_xor(s[q], 32);
        }
        if (slot == 0) {
            const float inv = (n > 0) ? 1.f / (float)n : 0.f;
            uint4 o;
            o.x = pack2bf(s[0] * inv, s[1] * inv);
            o.y = pack2bf(s[2] * inv, s[3] * inv);
            o.z = pack2bf(s[4] * inv, s[5] * inv);
            o.w = pack2bf(s[6] * inv, s[7] * inv);
            *(uint4*)(&ntile[dl][fl * 4]) = o;
        }
    }
    __syncthreads();

    // ---- Phase 2: MFMA stripe (16 rows x 128 cols, K=256), 1 tile/wave ----
    const int r = lane & 15, kg = lane >> 4;

    const unsigned int* ap = A_bf + (size_t)(rbase + r) * 64 + kg * 4;
    bf16x8 a[8];
#pragma unroll
    for (int s = 0; s < 4; ++s) a[s] = *(const bf16x8*)(ap + s * 16);
#pragma unroll
    for (int s = 0; s < 4; ++s) a[4 + s] = *(const bf16x8*)(&ntile[r][s * 16 + kg * 4]);

    bool hd[4];
#pragma unroll
    for (int q = 0; q < 4; ++q) hd[q] = h[kg * 4 + q] > 0;

    const int cbase = wave * 16;
    const unsigned int* bp = Bw + (size_t)(cbase + r) * 128 + kg * 4;
    bf16x8 bb[8];
#pragma unroll
    for (int s = 0; s < 8; ++s) bb[s] = *(const bf16x8*)(bp + s * 16);
    f32x4 acc = {0.f, 0.f, 0.f, 0.f};
#pragma unroll
    for (int s = 0; s < 8; ++s)
        acc = __builtin_amdgcn_mfma_f32_16x16x32_bf16(a[s], bb[s], acc, 0, 0, 0);

    const int col = cbase + r;
    const float bc = bfc[col], bs = bsrc2[col];
#pragma unroll
    for (int q = 0; q < 4; ++q) {
        const int row = rbase + kg * 4 + q;
        out[(size_t)row * DF + col] = acc[q] + bc + (hd[q] ? bs : 0.f);
    }
}

extern "C" void kernel_launch(void* const* d_in, const int* in_sizes, int n_in,
                              void* d_out, int out_size, void* d_ws, size_t ws_size,
                              hipStream_t stream) {
    const float* feat  = (const float*)d_in[0];
    const float* W_src = (const float*)d_in[1];
    const float* b_src = (const float*)d_in[2];
    const float* W_fc  = (const float*)d_in[3];
    const float* b_fc  = (const float*)d_in[4];
    const int*   src   = (const int*)d_in[5];
    const int*   dst   = (const int*)d_in[6];
    float* out = (float*)d_out;

    // ws: A_bf [NN*64 u32] | Bw [128*128 u32] | bsrc2 [128 f32] |
    //     off [NBUCK+1] | tbl [NTILES*NBUCK] | ents [NE u32]
    unsigned int* A_bf = (unsigned int*)d_ws;
    unsigned int* Bw = A_bf + (size_t)NN * 64;
    float* bsrc2 = (float*)(Bw + 128 * 128);
    int*   off   = (int*)(bsrc2 + 128);
    int*   tbl   = off + (NBUCK + 1);
    unsigned int* ents = (unsigned int*)(tbl + (size_t)NTILES * NBUCK);

    prologue    <<<PACK_BLKS + NTILES + PREP_BLKS, 1024, 0, stream>>>(
                    feat, A_bf, dst, tbl, W_fc, W_src, b_src, Bw, bsrc2);
    bin2        <<<NTILES, 1024, 0, stream>>>(src, dst, tbl, ents, off);
    gather_apply<<<NBUCK, 512, 0, stream>>>(A_bf, Bw, ents, off, b_fc, bsrc2, out);
}